// Round 1
// 200.361 us; speedup vs baseline: 1.0948x; 1.0948x over previous
//
#include <hip/hip_runtime.h>

#define AS1 __attribute__((address_space(1)))
#define AS3 __attribute__((address_space(3)))

typedef short short8 __attribute__((ext_vector_type(8)));
typedef float f32x16 __attribute__((ext_vector_type(16)));
typedef unsigned short ushort4v __attribute__((ext_vector_type(4)));

// Problem constants
#define BATCH 4096
#define IN_F 256
#define OUT_F 256
#define HYP 128
#define HX 129            // HYP + 1 (b2g folded in as extra channel, gain 1.0)
#define KP (HX * IN_F)    // 33024 shorts per V row
#define NBUILD (OUT_F * HX / 8)   // 4128 buildV blocks

__device__ __forceinline__ float bf2f(unsigned short u) {
  unsigned v = ((unsigned)u) << 16;
  float f;
  __builtin_memcpy(&f, &v, 4);
  return f;
}
__device__ __forceinline__ unsigned short f2bf(float f) {
  unsigned u;
  __builtin_memcpy(&u, &f, 4);
  unsigned r = u + 0x7fffu + ((u >> 16) & 1u);  // RTNE
  return (unsigned short)(r >> 16);
}

__device__ __forceinline__ void gld_lds16(const unsigned short* g, unsigned short* s) {
  __builtin_amdgcn_global_load_lds((const AS1 unsigned int*)g, (AS3 unsigned int*)s, 16, 0, 0);
}

// ---------------------------------------------------------------------------
// k_prep: fused prep. Blocks [0,256): hidden-layer GEMMs + bias GEMM + x->bf16
//         (formerly k_pre). Blocks [256, 256+NBUILD): V build (formerly
//         k_buildV). The two phases touch disjoint outputs; fusing overlaps
//         the BW-bound V build with the VALU-bound hidden GEMMs and removes
//         one launch serialization.
// ---------------------------------------------------------------------------
__global__ __launch_bounds__(256) void k_prep(
    const float* __restrict__ x,
    const float* __restrict__ W1g, const float* __restrict__ b1g,
    const float* __restrict__ W2g, const float* __restrict__ b2g,
    const float* __restrict__ W1b, const float* __restrict__ b1b,
    const float* __restrict__ W2b, const float* __restrict__ b2b,
    unsigned short* __restrict__ Vb,
    unsigned short* __restrict__ hgbT,
    unsigned short* __restrict__ xb,
    float* __restrict__ out) {
  __shared__ float xl[16 * IN_F];                 // 16 KB
  __shared__ float hbl[16 * HYP];                 // 8 KB  [row][h]
  __shared__ unsigned short hgt[HYP * 16];        // 4 KB  [h][row]
  const int t = threadIdx.x;

  if (blockIdx.x >= 256) {
    // ---- V build: V[o][h*256+i] = bf16( h<128 ? W2g[h][o*256+i] : b2g[o*256+i] )
    const int cid = (blockIdx.x - 256) * 256 + t;  // < 256*129*32
    const int ic = cid & 31;
    const int pair = cid >> 5;        // o*129 + h
    const int h = pair % HX;
    const int o = pair / HX;
    const float* src = (h < HYP) ? (W2g + (size_t)h * (OUT_F * IN_F) + o * IN_F + ic * 8)
                                 : (b2g + o * IN_F + ic * 8);
    const float4 v0 = ((const float4*)src)[0];
    const float4 v1 = ((const float4*)src)[1];
    uint4 pk;
    pk.x = (unsigned)f2bf(v0.x) | ((unsigned)f2bf(v0.y) << 16);
    pk.y = (unsigned)f2bf(v0.z) | ((unsigned)f2bf(v0.w) << 16);
    pk.z = (unsigned)f2bf(v1.x) | ((unsigned)f2bf(v1.y) << 16);
    pk.w = (unsigned)f2bf(v1.z) | ((unsigned)f2bf(v1.w) << 16);
    *(uint4*)(Vb + (size_t)o * KP + h * IN_F + ic * 8) = pk;
    return;
  }

  // ---- hidden GEMMs: 16 batch rows per block ----
  const int r0 = blockIdx.x * 16;
  for (int j0 = 0; j0 < 16 * IN_F; j0 += 256) {
    const float v = x[(size_t)r0 * IN_F + j0 + t];
    xl[j0 + t] = v;
    xb[(size_t)r0 * IN_F + j0 + t] = f2bf(v);
  }
  __syncthreads();
  const int h = t & 127;
  const int rb = (t >> 7) * 8;
  float ag[8] = {0.f, 0.f, 0.f, 0.f, 0.f, 0.f, 0.f, 0.f};
  float av[8] = {0.f, 0.f, 0.f, 0.f, 0.f, 0.f, 0.f, 0.f};
  for (int i = 0; i < IN_F; ++i) {
    const float wg = W1g[i * HYP + h];
    const float wb = W1b[i * HYP + h];
#pragma unroll
    for (int r = 0; r < 8; ++r) {
      const float xv = xl[(rb + r) * IN_F + i];
      ag[r] += xv * wg;
      av[r] += xv * wb;
    }
  }
  const float bg = b1g[h], bb = b1b[h];
#pragma unroll
  for (int r = 0; r < 8; ++r) {
    float g = ag[r] + bg; g = g > 0.f ? g : 0.f;
    float v = av[r] + bb; v = v > 0.f ? v : 0.f;
    hgt[h * 16 + rb + r] = f2bf(g);
    hbl[(rb + r) * HYP + h] = v;
  }
  __syncthreads();
  // coalesced-ish transposed store: hgbT[h][r0..r0+16)
  {
    const int h2 = t >> 1, part = t & 1;
    const uint4 pk = *(const uint4*)&hgt[h2 * 16 + part * 8];
    *(uint4*)&hgbT[(size_t)h2 * BATCH + r0 + part * 8] = pk;
  }
  // out init: out[r0+r][o=t] = b2b + sum_h hb*W2b
  float acc[16];
#pragma unroll
  for (int r = 0; r < 16; ++r) acc[r] = 0.f;
  for (int hh = 0; hh < HYP; ++hh) {
    const float w = W2b[hh * OUT_F + t];
#pragma unroll
    for (int r = 0; r < 16; ++r) acc[r] += hbl[r * HYP + hh] * w;
  }
  const float bo = b2b[t];
#pragma unroll
  for (int r = 0; r < 16; ++r) out[(size_t)(r0 + r) * OUT_F + t] = acc[r] + bo;
}

// ---------------------------------------------------------------------------
// k_gemm: out[b,o] += sum_h hg[b,h] * (sum_i V[o][h*256+i]*x[b,i])
// 512 threads = 8 waves: wave tile = 64 m-rows (wm = wave&3) x 32 o-cols
// (wo = wave>>2). Same per-CU LDS/MFMA/staging totals as the 256-thread
// version but 2 waves/SIMD (VGPR capped at 256 via __launch_bounds__(512,2))
// so ds_read->MFMA and staging latencies are hidden by the co-resident wave.
// Double-buffered 64 KB LDS B-tiles staged via global_load_lds width=16,
// issued one round ahead. XOR chunk swizzle (pos = chunk ^ (row&7)).
// hg scales in LDS; applied to fp32 accum at h-group flush (linearity).
// XCD-aware blockIdx remap: the 16 m-blocks sharing a (o-tile, z) V-slice
// land on one XCD (bid % 8 == group & 7) so each 1.06 MB slice is fetched
// into one L2 instead of ~4.
// ---------------------------------------------------------------------------
__global__ __launch_bounds__(512, 2) void k_gemm(const unsigned short* __restrict__ Vb,
                                                 const unsigned short* __restrict__ hgbT,
                                                 const unsigned short* __restrict__ xb,
                                                 float* __restrict__ out) {
  __shared__ __align__(16) unsigned short Bl[2][64 * 256];   // 2 x 32 KB
  __shared__ __align__(16) unsigned short hgs[33 * 256];     // 16.9 KB [h_local][m]
  const int tid = threadIdx.x;
  const int lane = tid & 63;
  const int wave = tid >> 6;        // 0..7
  const int l31 = lane & 31;
  const int hi = lane >> 5;
  const int wm = wave & 3;          // m-group (64 rows)
  const int wo = wave >> 2;         // o-half (32 cols)

  // XCD-aware decode: group g = (o-tile, z) pins to XCD g&7; x-blocks stack.
  const int bid = blockIdx.x;       // 0..255
  const int c = bid & 7;
  const int t2 = bid >> 3;
  const int xm = t2 & 15;           // m-block
  const int g8 = t2 >> 4;           // 0..1
  const int grp = c + 8 * g8;       // 0..15
  const int yo = grp & 3;
  const int z = grp >> 2;

  const int m0 = xm * 256;
  const int o0 = yo * 64;
  const int hBeg = (z * HX) >> 2;
  const int hEnd = ((z + 1) * HX) >> 2;
  const int nh = hEnd - hBeg;   // 32,32,32,33

  // ---- stage hg tile [h_local][m] (h==128 -> 1.0) ----
  for (int idx = tid; idx < nh * 256; idx += 512) {
    const int hl = idx >> 8;
    const int hh = hBeg + hl;
    hgs[idx] = (hh == HYP) ? (unsigned short)0x3F80
                           : hgbT[(size_t)hh * BATCH + m0 + (idx & 255)];
  }

  // ---- preload A fragments (2 m-subtiles x 16 k16-tiles), persistent ----
  const int mrow0 = m0 + wm * 64 + l31;
  const int mrow1 = mrow0 + 32;
  uint4 xf0[16], xf1[16];
#pragma unroll
  for (int j = 0; j < 16; ++j) {
    xf0[j] = *(const uint4*)(xb + (size_t)mrow0 * IN_F + j * 16 + hi * 8);
    xf1[j] = *(const uint4*)(xb + (size_t)mrow1 * IN_F + j * 16 + hi * 8);
  }

  // ---- staging geometry: 2048 chunks of 16B per round, 4 per thread ----
  const int nB = tid >> 5;            // base row (rows nB + 16j)
  const int p = tid & 31;             // stored position within row
  const int cs = p ^ (nB & 7);        // source chunk (XOR swizzle, self-inverse)
  const unsigned short* gsrc = Vb + (size_t)(o0 + nB) * KP + cs * 8 + (size_t)hBeg * IN_F;

  f32x16 zv;
#pragma unroll
  for (int i = 0; i < 16; ++i) zv[i] = 0.0f;
  f32x16 acc0 = zv, acc1 = zv;
  f32x16 ah0 = zv, ah1 = zv;

  // prologue: stage round 0 into buf 0
#pragma unroll
  for (int j = 0; j < 4; ++j)
    gld_lds16(gsrc + (size_t)j * 16 * KP, &Bl[0][(tid + 512 * j) * 8]);
  __syncthreads();

  for (int r = 0; r < nh; ++r) {
    const int buf = r & 1;
    if (r + 1 < nh) {  // issue next round's staging ahead of compute
      const unsigned short* gs = gsrc + (size_t)(r + 1) * IN_F;
#pragma unroll
      for (int j = 0; j < 4; ++j)
        gld_lds16(gs + (size_t)j * 16 * KP, &Bl[buf ^ 1][(tid + 512 * j) * 8]);
    }
    const unsigned short* bp = &Bl[buf][0];
    const int rowb = wo * 32 + l31;
#pragma unroll
    for (int ic = 0; ic < 4; ++ic) {
#pragma unroll
      for (int t = 0; t < 4; ++t) {
        const int c0 = ic * 8 + t * 2 + hi;
        const int pr = c0 ^ (l31 & 7);
        const short8 b0 = *(const short8*)(bp + rowb * 256 + pr * 8);
        const short8 a0 = __builtin_bit_cast(short8, xf0[ic * 4 + t]);
        const short8 a1 = __builtin_bit_cast(short8, xf1[ic * 4 + t]);
        ah0 = __builtin_amdgcn_mfma_f32_32x32x16_bf16(a0, b0, ah0, 0, 0, 0);
        ah1 = __builtin_amdgcn_mfma_f32_32x32x16_bf16(a1, b0, ah1, 0, 0, 0);
      }
    }
    // flush: acc += hg * ah (linearity: hg scale applied post-MFMA)
#pragma unroll
    for (int q = 0; q < 4; ++q) {
      const ushort4v v0 = *(const ushort4v*)&hgs[r * 256 + wm * 64 + 4 * hi + q * 8];
      const ushort4v v1 = *(const ushort4v*)&hgs[r * 256 + wm * 64 + 32 + 4 * hi + q * 8];
#pragma unroll
      for (int e = 0; e < 4; ++e) {
        acc0[q * 4 + e] += bf2f(v0[e]) * ah0[q * 4 + e];
        acc1[q * 4 + e] += bf2f(v1[e]) * ah1[q * 4 + e];
      }
    }
    ah0 = zv; ah1 = zv;
    __syncthreads();  // drains next-buf loads (issued ~1 round ago) + guards buf reuse
  }

  // epilogue: atomic accumulate (4 h-splits per output)
  const int mb = m0 + wm * 64 + 4 * hi;
  const int col = o0 + wo * 32 + l31;
#pragma unroll
  for (int g = 0; g < 16; ++g) {
    const int row0 = mb + (g & 3) + 8 * (g >> 2);
    atomicAdd(&out[(size_t)row0 * OUT_F + col], acc0[g]);
    atomicAdd(&out[(size_t)(row0 + 32) * OUT_F + col], acc1[g]);
  }
}

// ---------------------------------------------------------------------------
extern "C" void kernel_launch(void* const* d_in, const int* in_sizes, int n_in,
                              void* d_out, int out_size, void* d_ws, size_t ws_size,
                              hipStream_t stream) {
  const float* x = (const float*)d_in[0];
  const float* W1g = (const float*)d_in[1];
  const float* b1g = (const float*)d_in[2];
  const float* W2g = (const float*)d_in[3];
  const float* b2g = (const float*)d_in[4];
  const float* W1b = (const float*)d_in[5];
  const float* b1b = (const float*)d_in[6];
  const float* W2b = (const float*)d_in[7];
  const float* b2b = (const float*)d_in[8];
  float* out = (float*)d_out;

  char* ws = (char*)d_ws;
  const size_t szV = (size_t)OUT_F * KP * 2;        // 16,908,288
  const size_t szHg = (size_t)HYP * BATCH * 2;      //  1,048,576
  unsigned short* Vb = (unsigned short*)ws;
  unsigned short* hgbT = (unsigned short*)(ws + szV);
  unsigned short* xb = (unsigned short*)(ws + szV + szHg);

  hipLaunchKernelGGL(k_prep, dim3(256 + NBUILD), dim3(256), 0, stream,
                     x, W1g, b1g, W2g, b2g, W1b, b1b, W2b, b2b, Vb, hgbT, xb, out);
  hipLaunchKernelGGL(k_gemm, dim3(256), dim3(512), 0, stream,
                     Vb, hgbT, xb, out);
}

// Round 2
// 186.233 us; speedup vs baseline: 1.1778x; 1.0759x over previous
//
#include <hip/hip_runtime.h>

#define AS1 __attribute__((address_space(1)))
#define AS3 __attribute__((address_space(3)))

typedef short short8 __attribute__((ext_vector_type(8)));
typedef float f32x16 __attribute__((ext_vector_type(16)));
typedef unsigned short ushort4v __attribute__((ext_vector_type(4)));

// Problem constants
#define BATCH 4096
#define IN_F 256
#define OUT_F 256
#define HYP 128
#define HX 129            // HYP + 1 (b2g folded in as extra channel, gain 1.0)
#define KP (HX * IN_F)    // 33024 shorts per V row
#define NGEMMP 32         // prep GEMM blocks (M-tile 128)
#define NVB 516           // V-build blocks (2048 cids each; 256*129*32 / 2048)

__device__ __forceinline__ float bf2f(unsigned short u) {
  unsigned v = ((unsigned)u) << 16;
  float f;
  __builtin_memcpy(&f, &v, 4);
  return f;
}
__device__ __forceinline__ unsigned short f2bf(float f) {
  unsigned u;
  __builtin_memcpy(&u, &f, 4);
  unsigned r = u + 0x7fffu + ((u >> 16) & 1u);  // RTNE
  return (unsigned short)(r >> 16);
}

__device__ __forceinline__ void gld_lds16(const unsigned short* g, unsigned short* s) {
  __builtin_amdgcn_global_load_lds((const AS1 unsigned int*)g, (AS3 unsigned int*)s, 16, 0, 0);
}

// ---------------------------------------------------------------------------
// k_trans: build bf16 transposed weight views so MFMA operands are
// k-contiguous.  W1T[n][k] (n<128: W1g^T, n>=128: W1b^T), W2bT[o][h].
// Scattered 4B reads are L2-hot after the first pass; total 96K elements.
// ---------------------------------------------------------------------------
__global__ __launch_bounds__(256) void k_trans(const float* __restrict__ W1g,
                                               const float* __restrict__ W1b,
                                               const float* __restrict__ W2b,
                                               unsigned short* __restrict__ W1T,
                                               unsigned short* __restrict__ W2bT) {
  const int t = threadIdx.x, b = blockIdx.x;
  if (b < 64) {
#pragma unroll
    for (int i = 0; i < 4; ++i) {
      const int e = b * 1024 + i * 256 + t;   // < 65536
      const int n = e >> 8, k = e & 255;
      const float v = (n < HYP) ? W1g[k * HYP + n] : W1b[k * HYP + (n - HYP)];
      W1T[e] = f2bf(v);
    }
  } else {
#pragma unroll
    for (int i = 0; i < 4; ++i) {
      const int e = (b - 64) * 1024 + i * 256 + t;  // < 32768
      const int o = e >> 7, h = e & 127;
      W2bT[e] = f2bf(W2b[h * OUT_F + o]);
    }
  }
}

// ---------------------------------------------------------------------------
// k_prep: blocks [0,NGEMMP): MFMA prep GEMMs, M-tile 128, 8 waves.
//   GEMM1 (swapped): D1[h 256][m 128] = W1T . x^T  -> relu(+b1) ->
//     hgbT coalesced global stores (lane = m), hb -> swizzled LDS.
//   GEMM2: out[m][o] = hb @ W2bT + b2b, coalesced fp32 stores (lane = o).
//   x staged once: fp32 load -> bf16 -> xb global + XOR-swizzled LDS xS.
// blocks [NGEMMP, NGEMMP+NVB): V build (4 iters of the old 512-cid body).
// ---------------------------------------------------------------------------
__global__ __launch_bounds__(512) void k_prep(
    const float* __restrict__ x,
    const float* __restrict__ b1g, const float* __restrict__ b1b,
    const float* __restrict__ b2b,
    const float* __restrict__ W2g, const float* __restrict__ b2g,
    const unsigned short* __restrict__ W1T, const unsigned short* __restrict__ W2bT,
    unsigned short* __restrict__ Vb, unsigned short* __restrict__ hgbT,
    unsigned short* __restrict__ xb, float* __restrict__ out) {
  __shared__ __align__(16) unsigned short xS[128 * 256];   // 64 KB, chunk^row&31 swizzle
  __shared__ __align__(16) unsigned short hbS[128 * 128];  // 32 KB, chunk^m&15 swizzle
  const int t = threadIdx.x;

  if (blockIdx.x >= NGEMMP) {
    // ---- V build: V[o][h*256+i] = bf16( h<128 ? W2g[h][o*256+i] : b2g[o*256+i] )
    const int base = (blockIdx.x - NGEMMP) * 2048 + t;
#pragma unroll
    for (int it = 0; it < 4; ++it) {
      const int cid = base + it * 512;
      const int ic = cid & 31;
      const int pair = cid >> 5;        // o*129 + h
      const int h = pair % HX;
      const int o = pair / HX;
      const float* src = (h < HYP) ? (W2g + (size_t)h * (OUT_F * IN_F) + o * IN_F + ic * 8)
                                   : (b2g + o * IN_F + ic * 8);
      const float4 v0 = ((const float4*)src)[0];
      const float4 v1 = ((const float4*)src)[1];
      uint4 pk;
      pk.x = (unsigned)f2bf(v0.x) | ((unsigned)f2bf(v0.y) << 16);
      pk.y = (unsigned)f2bf(v0.z) | ((unsigned)f2bf(v0.w) << 16);
      pk.z = (unsigned)f2bf(v1.x) | ((unsigned)f2bf(v1.y) << 16);
      pk.w = (unsigned)f2bf(v1.z) | ((unsigned)f2bf(v1.w) << 16);
      *(uint4*)(Vb + (size_t)o * KP + h * IN_F + ic * 8) = pk;
    }
    return;
  }

  const int lane = t & 63;
  const int w = t >> 6;            // 0..7
  const int l31 = lane & 31;
  const int hi = lane >> 5;
  const int m0 = blockIdx.x * 128;

  // ---- stage x tile: fp32 -> bf16 -> xb global + swizzled LDS ----
#pragma unroll
  for (int j = 0; j < 16; ++j) {
    const int row = j * 8 + w;                       // 0..127, each once
    const float4 v = *(const float4*)(x + (size_t)(m0 + row) * IN_F + lane * 4);
    uint2 pk;
    pk.x = (unsigned)f2bf(v.x) | ((unsigned)f2bf(v.y) << 16);
    pk.y = (unsigned)f2bf(v.z) | ((unsigned)f2bf(v.w) << 16);
    *(uint2*)(xb + (size_t)(m0 + row) * IN_F + lane * 4) = pk;
    const int ch = lane >> 1, half = lane & 1;       // 16B chunk, 8B half
    *(uint2*)(&xS[row * 256 + ((ch ^ (row & 31))) * 8 + half * 4]) = pk;
  }
  __syncthreads();

  // ---- GEMM1 (swapped): D1[h = w*32+l31 .. ][m]; A = W1T rows, B = xS ----
  const int hA = w * 32 + l31;                       // 0..255 (g: <128, b: >=128)
  uint4 af[16];
#pragma unroll
  for (int kt = 0; kt < 16; ++kt)
    af[kt] = *(const uint4*)(W1T + (size_t)hA * 256 + kt * 16 + hi * 8);

  f32x16 zv;
#pragma unroll
  for (int i = 0; i < 16; ++i) zv[i] = 0.0f;
  f32x16 d0 = zv, d1 = zv, d2 = zv, d3 = zv;
#pragma unroll
  for (int kt = 0; kt < 16; ++kt) {
    const int pos = (kt * 2 + hi) ^ l31;             // (m&31) == l31 for all csub
    const short8 a = __builtin_bit_cast(short8, af[kt]);
#define G1STEP(CS, DD)                                                        \
    {                                                                         \
      const short8 bfrg = *(const short8*)(&xS[(CS * 32 + l31) * 256 + pos * 8]); \
      DD = __builtin_amdgcn_mfma_f32_32x32x16_bf16(a, bfrg, DD, 0, 0, 0);     \
    }
    G1STEP(0, d0) G1STEP(1, d1) G1STEP(2, d2) G1STEP(3, d3)
#undef G1STEP
  }

  // ---- epilogue1: relu(+b1); g-waves -> hgbT (coalesced), b-waves -> hbS ----
  if (w < 4) {
    float4 bq[4];
#pragma unroll
    for (int q = 0; q < 4; ++q)
      bq[q] = *(const float4*)(b1g + w * 32 + q * 8 + hi * 4);
#define EPI_G(CS, DD)                                                         \
    {                                                                         \
      const int mcol = m0 + CS * 32 + l31;                                    \
      _Pragma("unroll")                                                       \
      for (int g = 0; g < 16; ++g) {                                          \
        const int h = w * 32 + (g & 3) + 8 * (g >> 2) + 4 * hi;               \
        float v = DD[g] + ((const float*)&bq[g >> 2])[g & 3];                 \
        v = v > 0.f ? v : 0.f;                                                \
        hgbT[(size_t)h * BATCH + mcol] = f2bf(v);                             \
      }                                                                       \
    }
    EPI_G(0, d0) EPI_G(1, d1) EPI_G(2, d2) EPI_G(3, d3)
#undef EPI_G
  } else {
    float4 bq[4];
#pragma unroll
    for (int q = 0; q < 4; ++q)
      bq[q] = *(const float4*)(b1b + (w - 4) * 32 + q * 8 + hi * 4);
#define EPI_B(CS, DD)                                                         \
    {                                                                         \
      const int m = CS * 32 + l31;                                            \
      _Pragma("unroll")                                                       \
      for (int q = 0; q < 4; ++q) {                                           \
        float v0 = DD[q * 4 + 0] + ((const float*)&bq[q])[0];                 \
        float v1 = DD[q * 4 + 1] + ((const float*)&bq[q])[1];                 \
        float v2 = DD[q * 4 + 2] + ((const float*)&bq[q])[2];                 \
        float v3 = DD[q * 4 + 3] + ((const float*)&bq[q])[3];                 \
        v0 = v0 > 0.f ? v0 : 0.f; v1 = v1 > 0.f ? v1 : 0.f;                   \
        v2 = v2 > 0.f ? v2 : 0.f; v3 = v3 > 0.f ? v3 : 0.f;                   \
        uint2 pk;                                                             \
        pk.x = (unsigned)f2bf(v0) | ((unsigned)f2bf(v1) << 16);               \
        pk.y = (unsigned)f2bf(v2) | ((unsigned)f2bf(v3) << 16);               \
        const int chunk = (w - 4) * 4 + q;                                    \
        *(uint2*)(&hbS[m * 128 + ((chunk ^ (m & 15))) * 8 + hi * 4]) = pk;    \
      }                                                                       \
    }
    EPI_B(0, d0) EPI_B(1, d1) EPI_B(2, d2) EPI_B(3, d3)
#undef EPI_B
  }
  __syncthreads();

  // ---- GEMM2: out[m][o] = hbS @ W2bT + b2b (K = 128) ----
  const int msub = w & 3, oh = w >> 2;
  const int mA = msub * 32 + l31;
  f32x16 e0 = zv, e1 = zv, e2 = zv, e3 = zv;
#pragma unroll
  for (int kt = 0; kt < 8; ++kt) {
    const int pos = (kt * 2 + hi) ^ (mA & 15);
    const short8 a = *(const short8*)(&hbS[mA * 128 + pos * 8]);
#define G2STEP(OS, EE)                                                        \
    {                                                                         \
      const int orow = oh * 128 + OS * 32 + l31;                              \
      const short8 bb = *(const short8*)(W2bT + (size_t)orow * 128 + kt * 16 + hi * 8); \
      EE = __builtin_amdgcn_mfma_f32_32x32x16_bf16(a, bb, EE, 0, 0, 0);       \
    }
    G2STEP(0, e0) G2STEP(1, e1) G2STEP(2, e2) G2STEP(3, e3)
#undef G2STEP
  }
#define EPI2(OS, EE)                                                          \
  {                                                                           \
    const int o = oh * 128 + OS * 32 + l31;                                   \
    const float bo = b2b[o];                                                  \
    _Pragma("unroll")                                                         \
    for (int g = 0; g < 16; ++g) {                                            \
      const int m = m0 + msub * 32 + (g & 3) + 8 * (g >> 2) + 4 * hi;         \
      out[(size_t)m * OUT_F + o] = EE[g] + bo;                                \
    }                                                                         \
  }
  EPI2(0, e0) EPI2(1, e1) EPI2(2, e2) EPI2(3, e3)
#undef EPI2
}

// ---------------------------------------------------------------------------
// k_gemm: out[b,o] += sum_h hg[b,h] * (sum_i V[o][h*256+i]*x[b,i])
// UNCHANGED from previous round (verified): 512 threads = 8 waves, wave tile
// 64m x 32o, double-buffered LDS B-tiles via global_load_lds width=16, XOR
// chunk swizzle, hg scales applied at h-group flush, XCD-aware blockIdx
// remap, fp32 atomicAdd epilogue over 4 h-splits.
// ---------------------------------------------------------------------------
__global__ __launch_bounds__(512, 2) void k_gemm(const unsigned short* __restrict__ Vb,
                                                 const unsigned short* __restrict__ hgbT,
                                                 const unsigned short* __restrict__ xb,
                                                 float* __restrict__ out) {
  __shared__ __align__(16) unsigned short Bl[2][64 * 256];   // 2 x 32 KB
  __shared__ __align__(16) unsigned short hgs[33 * 256];     // 16.9 KB [h_local][m]
  const int tid = threadIdx.x;
  const int lane = tid & 63;
  const int wave = tid >> 6;        // 0..7
  const int l31 = lane & 31;
  const int hi = lane >> 5;
  const int wm = wave & 3;          // m-group (64 rows)
  const int wo = wave >> 2;         // o-half (32 cols)

  // XCD-aware decode: group g = (o-tile, z) pins to XCD g&7; x-blocks stack.
  const int bid = blockIdx.x;       // 0..255
  const int c = bid & 7;
  const int t2 = bid >> 3;
  const int xm = t2 & 15;           // m-block
  const int g8 = t2 >> 4;           // 0..1
  const int grp = c + 8 * g8;       // 0..15
  const int yo = grp & 3;
  const int z = grp >> 2;

  const int m0 = xm * 256;
  const int o0 = yo * 64;
  const int hBeg = (z * HX) >> 2;
  const int hEnd = ((z + 1) * HX) >> 2;
  const int nh = hEnd - hBeg;   // 32,32,32,33

  // ---- stage hg tile [h_local][m] (h==128 -> 1.0) ----
  for (int idx = tid; idx < nh * 256; idx += 512) {
    const int hl = idx >> 8;
    const int hh = hBeg + hl;
    hgs[idx] = (hh == HYP) ? (unsigned short)0x3F80
                           : hgbT[(size_t)hh * BATCH + m0 + (idx & 255)];
  }

  // ---- preload A fragments (2 m-subtiles x 16 k16-tiles), persistent ----
  const int mrow0 = m0 + wm * 64 + l31;
  const int mrow1 = mrow0 + 32;
  uint4 xf0[16], xf1[16];
#pragma unroll
  for (int j = 0; j < 16; ++j) {
    xf0[j] = *(const uint4*)(xb + (size_t)mrow0 * IN_F + j * 16 + hi * 8);
    xf1[j] = *(const uint4*)(xb + (size_t)mrow1 * IN_F + j * 16 + hi * 8);
  }

  // ---- staging geometry: 2048 chunks of 16B per round, 4 per thread ----
  const int nB = tid >> 5;            // base row (rows nB + 16j)
  const int p = tid & 31;             // stored position within row
  const int cs = p ^ (nB & 7);        // source chunk (XOR swizzle, self-inverse)
  const unsigned short* gsrc = Vb + (size_t)(o0 + nB) * KP + cs * 8 + (size_t)hBeg * IN_F;

  f32x16 zv;
#pragma unroll
  for (int i = 0; i < 16; ++i) zv[i] = 0.0f;
  f32x16 acc0 = zv, acc1 = zv;
  f32x16 ah0 = zv, ah1 = zv;

  // prologue: stage round 0 into buf 0
#pragma unroll
  for (int j = 0; j < 4; ++j)
    gld_lds16(gsrc + (size_t)j * 16 * KP, &Bl[0][(tid + 512 * j) * 8]);
  __syncthreads();

  for (int r = 0; r < nh; ++r) {
    const int buf = r & 1;
    if (r + 1 < nh) {  // issue next round's staging ahead of compute
      const unsigned short* gs = gsrc + (size_t)(r + 1) * IN_F;
#pragma unroll
      for (int j = 0; j < 4; ++j)
        gld_lds16(gs + (size_t)j * 16 * KP, &Bl[buf ^ 1][(tid + 512 * j) * 8]);
    }
    const unsigned short* bp = &Bl[buf][0];
    const int rowb = wo * 32 + l31;
#pragma unroll
    for (int ic = 0; ic < 4; ++ic) {
#pragma unroll
      for (int t = 0; t < 4; ++t) {
        const int c0 = ic * 8 + t * 2 + hi;
        const int pr = c0 ^ (l31 & 7);
        const short8 b0 = *(const short8*)(bp + rowb * 256 + pr * 8);
        const short8 a0 = __builtin_bit_cast(short8, xf0[ic * 4 + t]);
        const short8 a1 = __builtin_bit_cast(short8, xf1[ic * 4 + t]);
        ah0 = __builtin_amdgcn_mfma_f32_32x32x16_bf16(a0, b0, ah0, 0, 0, 0);
        ah1 = __builtin_amdgcn_mfma_f32_32x32x16_bf16(a1, b0, ah1, 0, 0, 0);
      }
    }
    // flush: acc += hg * ah (linearity: hg scale applied post-MFMA)
#pragma unroll
    for (int q = 0; q < 4; ++q) {
      const ushort4v v0 = *(const ushort4v*)&hgs[r * 256 + wm * 64 + 4 * hi + q * 8];
      const ushort4v v1 = *(const ushort4v*)&hgs[r * 256 + wm * 64 + 32 + 4 * hi + q * 8];
#pragma unroll
      for (int e = 0; e < 4; ++e) {
        acc0[q * 4 + e] += bf2f(v0[e]) * ah0[q * 4 + e];
        acc1[q * 4 + e] += bf2f(v1[e]) * ah1[q * 4 + e];
      }
    }
    ah0 = zv; ah1 = zv;
    __syncthreads();  // drains next-buf loads (issued ~1 round ago) + guards buf reuse
  }

  // epilogue: atomic accumulate (4 h-splits per output)
  const int mb = m0 + wm * 64 + 4 * hi;
  const int col = o0 + wo * 32 + l31;
#pragma unroll
  for (int g = 0; g < 16; ++g) {
    const int row0 = mb + (g & 3) + 8 * (g >> 2);
    atomicAdd(&out[(size_t)row0 * OUT_F + col], acc0[g]);
    atomicAdd(&out[(size_t)(row0 + 32) * OUT_F + col], acc1[g]);
  }
}

// ---------------------------------------------------------------------------
extern "C" void kernel_launch(void* const* d_in, const int* in_sizes, int n_in,
                              void* d_out, int out_size, void* d_ws, size_t ws_size,
                              hipStream_t stream) {
  const float* x = (const float*)d_in[0];
  const float* W1g = (const float*)d_in[1];
  const float* b1g = (const float*)d_in[2];
  const float* W2g = (const float*)d_in[3];
  const float* b2g = (const float*)d_in[4];
  const float* W1b = (const float*)d_in[5];
  const float* b1b = (const float*)d_in[6];
  const float* W2b = (const float*)d_in[7];
  const float* b2b = (const float*)d_in[8];
  float* out = (float*)d_out;

  char* ws = (char*)d_ws;
  const size_t szV = (size_t)OUT_F * KP * 2;        // 16,908,288
  const size_t szHg = (size_t)HYP * BATCH * 2;      //  1,048,576
  const size_t szXb = (size_t)BATCH * IN_F * 2;     //  2,097,152
  const size_t szW1T = (size_t)256 * 256 * 2;       //    131,072
  unsigned short* Vb = (unsigned short*)ws;
  unsigned short* hgbT = (unsigned short*)(ws + szV);
  unsigned short* xb = (unsigned short*)(ws + szV + szHg);
  unsigned short* W1T = (unsigned short*)(ws + szV + szHg + szXb);
  unsigned short* W2bT = (unsigned short*)(ws + szV + szHg + szXb + szW1T);

  hipLaunchKernelGGL(k_trans, dim3(96), dim3(256), 0, stream, W1g, W1b, W2b, W1T, W2bT);
  hipLaunchKernelGGL(k_prep, dim3(NGEMMP + NVB), dim3(512), 0, stream,
                     x, b1g, b1b, b2b, W2g, b2g, W1T, W2bT, Vb, hgbT, xb, out);
  hipLaunchKernelGGL(k_gemm, dim3(256), dim3(512), 0, stream, Vb, hgbT, xb, out);
}